// Round 1
// baseline (944.854 us; speedup 1.0000x reference)
//
#include <hip/hip_runtime.h>
#include <math.h>

// Problem constants (from reference)
#define NWAY   10
#define DIMD   64
#define HWN    49          // H*W = 7*7
#define NSUP   800         // N_WAY*K_SHOT*PRJ
#define NQRY   16000       // N_WAY*Q_QUERY*PRJ
#define NTRI   2080        // 64*65/2
#define FEAT_PER (DIMD*HWN) // 3136 floats per sample

struct __align__(16) BDCShared {
    float buf[DIMD*DIMD];   // 4096 floats: holds xT (3136, [m][d]) during Gram,
                            // then the centered/sqrt'd dcov matrix afterwards.
    float dg[DIMD];
    float rm[DIMD];         // row means == col means (dcov symmetric)
    float psum[4*DIMD];
    float red[4*NWAY];
    float tm;
};

// Map linear triu index k -> (i,j), j>=i, row-major triu of 64x64.
// off[i] = i*(129-i)/2 ; i = floor((129 - sqrt(129^2 - 8k))/2) with fixup.
__device__ __forceinline__ void k2ij(int k, int& io, int& jo) {
    int ii = (int)floorf((129.0f - sqrtf(16641.0f - 8.0f*(float)k)) * 0.5f);
    int off = ii*(129-ii)/2;
    if (off > k) { --ii; off = ii*(129-ii)/2; }
    else {
        int off2 = (ii+1)*(128-ii)/2;
        if (off2 <= k) { ii += 1; off = off2; }
    }
    io = ii;
    jo = ii + (k - off);
}

// Computes the centered BDC matrix for `sample` into sm.buf (full 64x64),
// row means into sm.rm, total mean returned. Block = 256 threads.
__device__ __forceinline__ float bdc_compute(const float* __restrict__ feat,
                                             float et, int sample,
                                             BDCShared& sm) {
    const int tid = threadIdx.x;

    // ---- Stage x into LDS, transposed: xT[m*64 + d] (coalesced float4 reads)
    float* xT = sm.buf;
    const float4* f4 = (const float4*)(feat + (size_t)sample * FEAT_PER);
    for (int idx = tid; idx < FEAT_PER/4; idx += 256) {
        float4 v = f4[idx];
        int e = idx * 4;
        #pragma unroll
        for (int kk = 0; kk < 4; ++kk) {
            int el = e + kk;
            int d = el / HWN;            // compiler magic-div
            int m = el - d * HWN;
            xT[m*DIMD + d] = (&v.x)[kk];
        }
    }
    __syncthreads();

    // ---- Gram: each thread owns a 4x4 tile of g = x x^T (16x16 thread grid)
    const int tx = tid & 15, ty = tid >> 4;
    float acc[4][4];
    #pragma unroll
    for (int r = 0; r < 4; ++r)
        #pragma unroll
        for (int c = 0; c < 4; ++c) acc[r][c] = 0.0f;

    for (int m = 0; m < HWN; ++m) {
        float4 a = *(const float4*)&xT[m*DIMD + 4*ty];  // rows i=4ty..4ty+3
        float4 b = *(const float4*)&xT[m*DIMD + 4*tx];  // cols j=4tx..4tx+3
        const float* ap = &a.x; const float* bp = &b.x;
        #pragma unroll
        for (int r = 0; r < 4; ++r)
            #pragma unroll
            for (int c = 0; c < 4; ++c)
                acc[r][c] = fmaf(ap[r], bp[c], acc[r][c]);
    }
    // diagonal of g (exact: g is bitwise symmetric by construction)
    if (tx == ty) {
        #pragma unroll
        for (int r = 0; r < 4; ++r) sm.dg[4*ty + r] = acc[r][r];
    }
    __syncthreads();   // all xT reads done; dg visible

    // ---- dcov = sqrt(et * max(dg_i + dg_j - 2 g_ij, 0) + 1e-5), overwrite buf
    float* g = sm.buf;
    #pragma unroll
    for (int r = 0; r < 4; ++r) {
        int i = 4*ty + r;
        float dgi = sm.dg[i];
        #pragma unroll
        for (int c = 0; c < 4; ++c) {
            int j = 4*tx + c;
            float val = dgi + sm.dg[j] - 2.0f*acc[r][c];
            g[i*DIMD + j] = sqrtf(et * fmaxf(val, 0.0f) + 1e-5f);
        }
    }
    __syncthreads();

    // ---- column sums (== row sums by symmetry); bank = lane&31, conflict-free
    {
        int c = tid & 63, q = tid >> 6;
        float s = 0.0f;
        #pragma unroll
        for (int i2 = 0; i2 < 16; ++i2) s += g[(q*16 + i2)*DIMD + c];
        sm.psum[q*DIMD + c] = s;
    }
    __syncthreads();
    if (tid < DIMD) {
        sm.rm[tid] = (sm.psum[tid] + sm.psum[DIMD+tid] +
                      sm.psum[2*DIMD+tid] + sm.psum[3*DIMD+tid]) * (1.0f/64.0f);
    }
    __syncthreads();
    if (tid < DIMD) {   // threads 0..63 = one full wave
        float v = sm.rm[tid];
        #pragma unroll
        for (int o = 32; o > 0; o >>= 1) v += __shfl_xor(v, o, 64);
        if (tid == 0) sm.tm = v * (1.0f/64.0f);
    }
    __syncthreads();
    return sm.tm;
}

__global__ void kern_zero(float* __restrict__ p, int n) {
    int i = blockIdx.x * 256 + threadIdx.x;
    if (i < n) p[i] = 0.0f;
}

// Support samples: accumulate class prototype means via atomicAdd (v/80).
__global__ __launch_bounds__(256) void kern_support(const float* __restrict__ feat,
                                                    const float* __restrict__ temp,
                                                    float* __restrict__ support) {
    __shared__ BDCShared sm;
    float et = expf(temp[0]);
    int s = blockIdx.x;                 // 0..799
    float tm = bdc_compute(feat, et, s, sm);
    float* dst = support + (s / 80) * NTRI;
    for (int k = threadIdx.x; k < NTRI; k += 256) {
        int i, j; k2ij(k, i, j);
        float v = sm.buf[i*DIMD + j] - sm.rm[i] - sm.rm[j] + tm;
        atomicAdd(&dst[k], v * (1.0f/80.0f));
    }
}

// Query samples: BDC in LDS, then score[m] = -sum_k (q_k - s_mk)^2 directly.
__global__ __launch_bounds__(256) void kern_query(const float* __restrict__ feat,
                                                  const float* __restrict__ temp,
                                                  const float* __restrict__ support,
                                                  float* __restrict__ out) {
    __shared__ BDCShared sm;
    float et = expf(temp[0]);
    int qn = blockIdx.x;                // 0..15999
    float tm = bdc_compute(feat, et, NSUP + qn, sm);

    float acc[NWAY];
    #pragma unroll
    for (int m = 0; m < NWAY; ++m) acc[m] = 0.0f;

    for (int k = threadIdx.x; k < NTRI; k += 256) {
        int i, j; k2ij(k, i, j);
        float v = sm.buf[i*DIMD + j] - sm.rm[i] - sm.rm[j] + tm;
        #pragma unroll
        for (int m = 0; m < NWAY; ++m) {
            float d = v - support[m*NTRI + k];   // coalesced, L2-resident
            acc[m] = fmaf(d, d, acc[m]);
        }
    }

    // block reduction: wave butterfly, then 4 wave-leaders through LDS
    int lane = threadIdx.x & 63, wv = threadIdx.x >> 6;
    #pragma unroll
    for (int m = 0; m < NWAY; ++m) {
        float v = acc[m];
        #pragma unroll
        for (int o = 32; o > 0; o >>= 1) v += __shfl_xor(v, o, 64);
        acc[m] = v;
    }
    if (lane == 0) {
        #pragma unroll
        for (int m = 0; m < NWAY; ++m) sm.red[wv*NWAY + m] = acc[m];
    }
    __syncthreads();
    if (threadIdx.x < NWAY) {
        int m = threadIdx.x;
        float ssum = sm.red[m] + sm.red[NWAY + m] + sm.red[2*NWAY + m] + sm.red[3*NWAY + m];
        out[(size_t)qn * NWAY + m] = -ssum;
    }
}

// Softmax NLL: loss = mean_n( logsumexp(score_n) - score_n[label_n] )
__global__ __launch_bounds__(256) void kern_loss(const float* __restrict__ score,
                                                 const int* __restrict__ label,
                                                 float* __restrict__ loss_out) {
    __shared__ float red[4];
    float lsum = 0.0f;
    for (int n = threadIdx.x; n < NQRY; n += 256) {
        const float* srow = score + (size_t)n * NWAY;
        float s[NWAY];
        float mx = -1e30f;
        #pragma unroll
        for (int m = 0; m < NWAY; ++m) { s[m] = srow[m]; mx = fmaxf(mx, s[m]); }
        float se = 0.0f;
        #pragma unroll
        for (int m = 0; m < NWAY; ++m) se += expf(s[m] - mx);
        float lse = mx + logf(se);
        lsum += lse - s[label[n]];
    }
    int lane = threadIdx.x & 63, wv = threadIdx.x >> 6;
    #pragma unroll
    for (int o = 32; o > 0; o >>= 1) lsum += __shfl_xor(lsum, o, 64);
    if (lane == 0) red[wv] = lsum;
    __syncthreads();
    if (threadIdx.x == 0)
        loss_out[0] = (red[0] + red[1] + red[2] + red[3]) * (1.0f / (float)NQRY);
}

extern "C" void kernel_launch(void* const* d_in, const int* in_sizes, int n_in,
                              void* d_out, int out_size, void* d_ws, size_t ws_size,
                              hipStream_t stream) {
    const float* feat = (const float*)d_in[0];
    const float* temp = (const float*)d_in[1];
    const int*   label = (const int*)d_in[2];
    float* out = (float*)d_out;
    float* support = (float*)d_ws;          // NWAY*NTRI = 20800 floats (83 KB)

    kern_zero<<<(NWAY*NTRI + 255)/256, 256, 0, stream>>>(support, NWAY*NTRI);
    kern_support<<<NSUP, 256, 0, stream>>>(feat, temp, support);
    kern_query<<<NQRY, 256, 0, stream>>>(feat, temp, support, out);
    kern_loss<<<1, 256, 0, stream>>>(out, label, out + (size_t)NQRY*NWAY);
}

// Round 2
// 461.841 us; speedup vs baseline: 2.0458x; 2.0458x over previous
//
#include <hip/hip_runtime.h>
#include <math.h>

// Problem constants (from reference)
#define NWAY   10
#define DIMD   64
#define HWN    49           // H*W = 7*7
#define NSUP   800          // N_WAY*K_SHOT*PRJ
#define NQRY   16000        // N_WAY*Q_QUERY*PRJ
#define NTRI   2080         // 64*65/2
#define FEAT_PER (DIMD*HWN) // 3136 floats per sample
#define LDST   68           // padded LDS row stride (floats): 68%4==0 keeps
                            // float4 alignment; 68m mod 32 = 4m rotates banks
                            // across rows (stride 64 put 12+ lanes in 1 bank)

struct __align__(16) BDCShared {
    float buf[DIMD*LDST];   // 4352 floats: xT (49 rows x 68) during Gram,
                            // then the sqrt'd dcov matrix (64 rows x 68).
    float dg[DIMD];
    float rm[DIMD];         // row means == col means (dcov symmetric)
    float psum[4*DIMD];
    float red[4*NWAY];
    float tm;
};

// Map linear triu index k -> (i,j), j>=i, row-major triu of 64x64.
__device__ __forceinline__ void k2ij(int k, int& io, int& jo) {
    int ii = (int)floorf((129.0f - sqrtf(16641.0f - 8.0f*(float)k)) * 0.5f);
    int off = ii*(129-ii)/2;
    if (off > k) { --ii; off = ii*(129-ii)/2; }
    else {
        int off2 = (ii+1)*(128-ii)/2;
        if (off2 <= k) { ii += 1; off = off2; }
    }
    io = ii;
    jo = ii + (k - off);
}

// Computes the sqrt'd dcov matrix for `sample` into sm.buf (64 x LDST),
// row means into sm.rm, total mean returned. Block = 256 threads.
__device__ __forceinline__ float bdc_compute(const float* __restrict__ feat,
                                             float et, int sample,
                                             BDCShared& sm) {
    const int tid = threadIdx.x;

    // ---- Stage x into LDS, transposed: xT[m*LDST + d] (coalesced float4 in)
    float* xT = sm.buf;
    const float4* f4 = (const float4*)(feat + (size_t)sample * FEAT_PER);
    for (int idx = tid; idx < FEAT_PER/4; idx += 256) {
        float4 v = f4[idx];
        int e = idx * 4;
        #pragma unroll
        for (int kk = 0; kk < 4; ++kk) {
            int el = e + kk;
            int d = el / HWN;            // compiler magic-div
            int m = el - d * HWN;
            xT[m*LDST + d] = (&v.x)[kk];
        }
    }
    __syncthreads();

    // ---- Gram: each thread owns a 4x4 tile of g = x x^T (16x16 thread grid)
    const int tx = tid & 15, ty = tid >> 4;
    float acc[4][4];
    #pragma unroll
    for (int r = 0; r < 4; ++r)
        #pragma unroll
        for (int c = 0; c < 4; ++c) acc[r][c] = 0.0f;

    #pragma unroll 7
    for (int m = 0; m < HWN; ++m) {
        float4 a = *(const float4*)&xT[m*LDST + 4*ty];  // rows i: broadcast x16
        float4 b = *(const float4*)&xT[m*LDST + 4*tx];  // cols j: 2-way (free)
        const float* ap = &a.x; const float* bp = &b.x;
        #pragma unroll
        for (int r = 0; r < 4; ++r)
            #pragma unroll
            for (int c = 0; c < 4; ++c)
                acc[r][c] = fmaf(ap[r], bp[c], acc[r][c]);
    }
    // diagonal of g (exact: g is bitwise symmetric by construction)
    if (tx == ty) {
        #pragma unroll
        for (int r = 0; r < 4; ++r) sm.dg[4*ty + r] = acc[r][r];
    }
    __syncthreads();   // all xT reads done; dg visible

    // ---- dcov = sqrt(et*max(dg_i+dg_j-2g_ij,0)+1e-5), overwrite buf.
    //      float4 row stores (was 16 scalar stores at 8-way bank conflict).
    float* g = sm.buf;
    #pragma unroll
    for (int r = 0; r < 4; ++r) {
        int i = 4*ty + r;
        float dgi = sm.dg[i];
        float4 w;
        #pragma unroll
        for (int c = 0; c < 4; ++c) {
            float val = dgi + sm.dg[4*tx + c] - 2.0f*acc[r][c];
            (&w.x)[c] = sqrtf(et * fmaxf(val, 0.0f) + 1e-5f);
        }
        *(float4*)&g[i*LDST + 4*tx] = w;
    }
    __syncthreads();

    // ---- column sums (== row sums by symmetry)
    {
        int c = tid & 63, q = tid >> 6;
        float s = 0.0f;
        #pragma unroll
        for (int i2 = 0; i2 < 16; ++i2) s += g[(q*16 + i2)*LDST + c];
        sm.psum[q*DIMD + c] = s;
    }
    __syncthreads();
    if (tid < DIMD) {
        sm.rm[tid] = (sm.psum[tid] + sm.psum[DIMD+tid] +
                      sm.psum[2*DIMD+tid] + sm.psum[3*DIMD+tid]) * (1.0f/64.0f);
    }
    __syncthreads();
    if (tid < DIMD) {   // threads 0..63 = one full wave
        float v = sm.rm[tid];
        #pragma unroll
        for (int o = 32; o > 0; o >>= 1) v += __shfl_xor(v, o, 64);
        if (tid == 0) sm.tm = v * (1.0f/64.0f);
    }
    __syncthreads();
    return sm.tm;
}

__global__ void kern_zero(float* __restrict__ support, float* __restrict__ loss_slot) {
    int i = blockIdx.x * 256 + threadIdx.x;
    if (i < NWAY*NTRI) support[i] = 0.0f;
    if (i == NWAY*NTRI) loss_slot[0] = 0.0f;
}

// Support samples: accumulate class prototype means via atomicAdd (v/80).
__global__ __launch_bounds__(256, 4) void kern_support(const float* __restrict__ feat,
                                                       const float* __restrict__ temp,
                                                       float* __restrict__ support) {
    __shared__ BDCShared sm;
    float et = expf(temp[0]);
    int s = blockIdx.x;                 // 0..799
    float tm = bdc_compute(feat, et, s, sm);
    float* dst = support + (s / 80) * NTRI;
    for (int k = threadIdx.x; k < NTRI; k += 256) {
        int i, j; k2ij(k, i, j);
        float v = sm.buf[i*LDST + j] - sm.rm[i] - sm.rm[j] + tm;
        atomicAdd(&dst[k], v * (1.0f/80.0f));
    }
}

// Query samples: BDC in LDS, then score[m] = -sum_k (q_k - s_mk)^2 directly.
__global__ __launch_bounds__(256, 4) void kern_query(const float* __restrict__ feat,
                                                     const float* __restrict__ temp,
                                                     const float* __restrict__ support,
                                                     float* __restrict__ out) {
    __shared__ BDCShared sm;
    float et = expf(temp[0]);
    int qn = blockIdx.x;                // 0..15999
    float tm = bdc_compute(feat, et, NSUP + qn, sm);

    float acc[NWAY];
    #pragma unroll
    for (int m = 0; m < NWAY; ++m) acc[m] = 0.0f;

    for (int k = threadIdx.x; k < NTRI; k += 256) {
        int i, j; k2ij(k, i, j);
        float v = sm.buf[i*LDST + j] - sm.rm[i] - sm.rm[j] + tm;
        #pragma unroll
        for (int m = 0; m < NWAY; ++m) {
            float d = v - support[m*NTRI + k];   // coalesced, L2-resident
            acc[m] = fmaf(d, d, acc[m]);
        }
    }

    // block reduction: wave butterfly, then 4 wave-leaders through LDS
    int lane = threadIdx.x & 63, wv = threadIdx.x >> 6;
    #pragma unroll
    for (int m = 0; m < NWAY; ++m) {
        float v = acc[m];
        #pragma unroll
        for (int o = 32; o > 0; o >>= 1) v += __shfl_xor(v, o, 64);
        acc[m] = v;
    }
    if (lane == 0) {
        #pragma unroll
        for (int m = 0; m < NWAY; ++m) sm.red[wv*NWAY + m] = acc[m];
    }
    __syncthreads();
    if (threadIdx.x < NWAY) {
        int m = threadIdx.x;
        float ssum = sm.red[m] + sm.red[NWAY + m] + sm.red[2*NWAY + m] + sm.red[3*NWAY + m];
        out[(size_t)qn * NWAY + m] = -ssum;
    }
}

// Softmax NLL partials: 63 blocks x 256 rows, one atomicAdd per block.
__global__ __launch_bounds__(256) void kern_loss(const float* __restrict__ score,
                                                 const int* __restrict__ label,
                                                 float* __restrict__ loss_out) {
    __shared__ float red[4];
    int n = blockIdx.x * 256 + threadIdx.x;
    float lsum = 0.0f;
    if (n < NQRY) {
        const float* srow = score + (size_t)n * NWAY;
        float s[NWAY];
        float mx = -1e30f;
        #pragma unroll
        for (int m = 0; m < NWAY; ++m) { s[m] = srow[m]; mx = fmaxf(mx, s[m]); }
        float se = 0.0f;
        #pragma unroll
        for (int m = 0; m < NWAY; ++m) se += expf(s[m] - mx);
        float lse = mx + logf(se);
        lsum = lse - s[label[n]];
    }
    int lane = threadIdx.x & 63, wv = threadIdx.x >> 6;
    #pragma unroll
    for (int o = 32; o > 0; o >>= 1) lsum += __shfl_xor(lsum, o, 64);
    if (lane == 0) red[wv] = lsum;
    __syncthreads();
    if (threadIdx.x == 0)
        atomicAdd(loss_out, (red[0] + red[1] + red[2] + red[3]) * (1.0f / (float)NQRY));
}

extern "C" void kernel_launch(void* const* d_in, const int* in_sizes, int n_in,
                              void* d_out, int out_size, void* d_ws, size_t ws_size,
                              hipStream_t stream) {
    const float* feat = (const float*)d_in[0];
    const float* temp = (const float*)d_in[1];
    const int*   label = (const int*)d_in[2];
    float* out = (float*)d_out;
    float* support = (float*)d_ws;          // NWAY*NTRI = 20800 floats (83 KB)
    float* loss_slot = out + (size_t)NQRY * NWAY;

    kern_zero<<<(NWAY*NTRI + 256)/256, 256, 0, stream>>>(support, loss_slot);
    kern_support<<<NSUP, 256, 0, stream>>>(feat, temp, support);
    kern_query<<<NQRY, 256, 0, stream>>>(feat, temp, support, out);
    kern_loss<<<(NQRY + 255)/256, 256, 0, stream>>>(out, label, loss_slot);
}

// Round 4
// 385.660 us; speedup vs baseline: 2.4500x; 1.1975x over previous
//
#include <hip/hip_runtime.h>
#include <math.h>

// Problem constants (from reference)
#define NWAY   10
#define DIMD   64
#define HWN    49           // H*W = 7*7
#define NSUP   800          // N_WAY*K_SHOT*PRJ
#define NQRY   16000        // N_WAY*Q_QUERY*PRJ
#define NTRI   2080         // 64*65/2
#define FEAT_PER (DIMD*HWN) // 3136 floats per sample
#define LDST   68           // fp32 dcov row stride (bank rotation, 16B-aligned)
#define KPAD   72           // bf16 row stride: 144 B/row -> 4-bank rotation,
                            // 16B-aligned fragment reads, 2-way conflict max

typedef __attribute__((ext_vector_type(8))) short bf16x8;
typedef __attribute__((ext_vector_type(4))) float f32x4;

struct __align__(16) BDCShared {
    union {
        float dcov[DIMD*LDST];                 // 17408 B (sqrt'd BDC matrix)
        unsigned short hl[2*DIMD*KPAD];        // 18432 B: H[64][72], L[64][72]
    } u;
    float dg[DIMD];
    float rm[DIMD];
    float psum[4*DIMD];
    float red[4*12];        // per-wave partials: 10 cross + 1 qq
    float tm;
};

// Map linear triu index k -> (i,j), j>=i, row-major triu of 64x64 (init only).
__device__ __forceinline__ void k2ij(int k, int& io, int& jo) {
    int ii = (int)floorf((129.0f - sqrtf(16641.0f - 8.0f*(float)k)) * 0.5f);
    int off = ii*(129-ii)/2;
    if (off > k) { --ii; off = ii*(129-ii)/2; }
    else {
        int off2 = (ii+1)*(128-ii)/2;
        if (off2 <= k) { ii += 1; off = off2; }
    }
    io = ii;
    jo = ii + (k - off);
}

__device__ __forceinline__ unsigned short f32_to_bf16_rn(float x) {
    unsigned u = __float_as_uint(x);
    return (unsigned short)((u + 0x7fffu + ((u >> 16) & 1u)) >> 16);
}

// MFMA-based BDC: writes sqrt'd dcov (uncentered) into sm.u.dcov, row means
// into sm.rm, returns total mean. Block = 256 threads = 4 waves.
__device__ __forceinline__ float bdc_compute(const float* __restrict__ feat,
                                             float et, int sample,
                                             BDCShared& sm) {
    const int tid = threadIdx.x;
    unsigned short* H = sm.u.hl;
    unsigned short* Lp = sm.u.hl + DIMD*KPAD;

    // ---- Stage: fp32 -> (H,L) bf16 split, layout [d][k] (k = spatial index)
    const float4* f4 = (const float4*)(feat + (size_t)sample * FEAT_PER);
    for (int idx = tid; idx < FEAT_PER/4; idx += 256) {
        float4 v = f4[idx];
        int e = idx * 4;
        #pragma unroll
        for (int kk = 0; kk < 4; ++kk) {
            int el = e + kk;
            int d = el / HWN;            // magic-div
            int m = el - d * HWN;
            float x = (&v.x)[kk];
            unsigned short hu = f32_to_bf16_rn(x);
            float hf = __uint_as_float(((unsigned)hu) << 16);
            unsigned short lu = f32_to_bf16_rn(x - hf);
            H[d*KPAD + m]  = hu;
            Lp[d*KPAD + m] = lu;
        }
    }
    // zero-pad k = 49..63 (MFMA consumes K=64)
    for (int p = tid; p < DIMD*16; p += 256) {
        int d = p >> 4, k = 48 + (p & 15);
        if (k >= HWN) { H[d*KPAD + k] = 0; Lp[d*KPAD + k] = 0; }
    }
    __syncthreads();

    // ---- Gram via MFMA 16x16x32 bf16. Wave w owns G rows 16w..16w+15.
    // A-frag = X[16w + (lane&15)][quad*8 + j (+32*kstep)]; B-frag same form
    // from row-block J. k-permutation cancels between A and B.
    const int wv = tid >> 6, lane = tid & 63;
    const int qd = lane >> 4, c15 = lane & 15;
    const int abase = (16*wv + c15)*KPAD + qd*8;
    bf16x8 AH0 = *(const bf16x8*)&H[abase];
    bf16x8 AH1 = *(const bf16x8*)&H[abase + 32];
    bf16x8 AL0 = *(const bf16x8*)&Lp[abase];
    bf16x8 AL1 = *(const bf16x8*)&Lp[abase + 32];

    f32x4 acc[4];
    #pragma unroll
    for (int J = 0; J < 4; ++J) {
        const int bbase = (16*J + c15)*KPAD + qd*8;
        bf16x8 BH0 = *(const bf16x8*)&H[bbase];
        bf16x8 BH1 = *(const bf16x8*)&H[bbase + 32];
        bf16x8 BL0 = *(const bf16x8*)&Lp[bbase];
        bf16x8 BL1 = *(const bf16x8*)&Lp[bbase + 32];
        f32x4 a = {0.f, 0.f, 0.f, 0.f};
        a = __builtin_amdgcn_mfma_f32_16x16x32_bf16(AH0, BH0, a, 0, 0, 0);
        a = __builtin_amdgcn_mfma_f32_16x16x32_bf16(AH1, BH1, a, 0, 0, 0);
        a = __builtin_amdgcn_mfma_f32_16x16x32_bf16(AL0, BH0, a, 0, 0, 0);
        a = __builtin_amdgcn_mfma_f32_16x16x32_bf16(AL1, BH1, a, 0, 0, 0);
        a = __builtin_amdgcn_mfma_f32_16x16x32_bf16(AH0, BL0, a, 0, 0, 0);
        a = __builtin_amdgcn_mfma_f32_16x16x32_bf16(AH1, BL1, a, 0, 0, 0);
        acc[J] = a;
    }

    // ---- dg from G diagonal (tile J == wv). C/D: col=lane&15, row=quad*4+reg.
    #pragma unroll
    for (int J = 0; J < 4; ++J) {
        if (J == wv) {
            #pragma unroll
            for (int r = 0; r < 4; ++r)
                if (c15 == 4*qd + r) sm.dg[16*wv + c15] = acc[J][r];
        }
    }
    __syncthreads();   // dg visible; all frag reads done -> union reuse safe

    // ---- dcov = sqrt(et*max(dg_i+dg_j-2g,0)+1e-5) into union (overwrites H/L)
    float* dcov = sm.u.dcov;
    float dgi[4];
    #pragma unroll
    for (int r = 0; r < 4; ++r) dgi[r] = sm.dg[16*wv + 4*qd + r];
    #pragma unroll
    for (int J = 0; J < 4; ++J) {
        int j = 16*J + c15;
        float dgj = sm.dg[j];
        #pragma unroll
        for (int r = 0; r < 4; ++r) {
            int i = 16*wv + 4*qd + r;
            float val = dgi[r] + dgj - 2.0f*acc[J][r];
            dcov[i*LDST + j] = sqrtf(et * fmaxf(val, 0.0f) + 1e-5f);
        }
    }
    __syncthreads();

    // ---- column sums (== row sums by symmetry) -> rm, tm
    {
        int c = tid & 63, q = tid >> 6;
        float s = 0.0f;
        #pragma unroll
        for (int i2 = 0; i2 < 16; ++i2) s += dcov[(q*16 + i2)*LDST + c];
        sm.psum[q*DIMD + c] = s;
    }
    __syncthreads();
    if (tid < DIMD) {
        sm.rm[tid] = (sm.psum[tid] + sm.psum[DIMD+tid] +
                      sm.psum[2*DIMD+tid] + sm.psum[3*DIMD+tid]) * (1.0f/64.0f);
    }
    __syncthreads();
    if (tid < DIMD) {
        float v = sm.rm[tid];
        #pragma unroll
        for (int o = 32; o > 0; o >>= 1) v += __shfl_xor(v, o, 64);
        if (tid == 0) sm.tm = v * (1.0f/64.0f);
    }
    __syncthreads();
    return sm.tm;
}

// init: zero support + loss slot, build triu table (addr<<16 | i<<8 | j)
__global__ void kern_init(float* __restrict__ support,
                          unsigned* __restrict__ table,
                          float* __restrict__ loss_slot) {
    int i = blockIdx.x * 256 + threadIdx.x;
    if (i < NWAY*NTRI) support[i] = 0.0f;
    if (i < NTRI) {
        int ii, jj; k2ij(i, ii, jj);
        table[i] = ((unsigned)(ii*LDST + jj) << 16) | ((unsigned)ii << 8) | (unsigned)jj;
    }
    if (i == 0) loss_slot[0] = 0.0f;
}

__global__ __launch_bounds__(256, 6) void kern_support(const float* __restrict__ feat,
                                                       const float* __restrict__ temp,
                                                       const unsigned* __restrict__ table,
                                                       float* __restrict__ support) {
    __shared__ BDCShared sm;
    float et = __expf(temp[0]);
    int s = blockIdx.x;                 // 0..799
    float tm = bdc_compute(feat, et, s, sm);
    float* dst = support + (s / 80) * NTRI;
    for (int k = threadIdx.x; k < NTRI; k += 256) {
        unsigned t = table[k];
        float v = sm.u.dcov[t >> 16] - sm.rm[(t >> 8) & 63] - sm.rm[t & 63] + tm;
        atomicAdd(&dst[k], v * (1.0f/80.0f));
    }
}

// s2[m] = sum_triu S_m^2 (after support fully accumulated). Grid = NWAY.
__global__ __launch_bounds__(256) void kern_s2(const float* __restrict__ support,
                                               float* __restrict__ s2) {
    __shared__ float red[4];
    int m = blockIdx.x;
    const float* S = support + m * NTRI;
    float acc = 0.0f;
    for (int k = threadIdx.x; k < NTRI; k += 256) acc = fmaf(S[k], S[k], acc);
    int lane = threadIdx.x & 63, wv = threadIdx.x >> 6;
    #pragma unroll
    for (int o = 32; o > 0; o >>= 1) acc += __shfl_xor(acc, o, 64);
    if (lane == 0) red[wv] = acc;
    __syncthreads();
    if (threadIdx.x == 0) s2[m] = red[0] + red[1] + red[2] + red[3];
}

// Query: BDC -> score_m = -(qq + s2[m] - 2*cross[m])  (reference's own form)
__global__ __launch_bounds__(256, 6) void kern_query(const float* __restrict__ feat,
                                                     const float* __restrict__ temp,
                                                     const unsigned* __restrict__ table,
                                                     const float* __restrict__ support,
                                                     const float* __restrict__ s2,
                                                     float* __restrict__ out) {
    __shared__ BDCShared sm;
    float et = __expf(temp[0]);
    int qn = blockIdx.x;                // 0..15999
    float tm = bdc_compute(feat, et, NSUP + qn, sm);

    float qq = 0.0f;
    float cr[NWAY];
    #pragma unroll
    for (int m = 0; m < NWAY; ++m) cr[m] = 0.0f;

    for (int k = threadIdx.x; k < NTRI; k += 256) {
        unsigned t = table[k];
        float v = sm.u.dcov[t >> 16] - sm.rm[(t >> 8) & 63] - sm.rm[t & 63] + tm;
        qq = fmaf(v, v, qq);
        #pragma unroll
        for (int m = 0; m < NWAY; ++m)
            cr[m] = fmaf(v, support[m*NTRI + k], cr[m]);
    }

    // reduce 11 accumulators: wave butterfly + cross-wave via LDS
    int lane = threadIdx.x & 63, wv = threadIdx.x >> 6;
    #pragma unroll
    for (int m = 0; m < NWAY; ++m) {
        float v = cr[m];
        #pragma unroll
        for (int o = 32; o > 0; o >>= 1) v += __shfl_xor(v, o, 64);
        cr[m] = v;
    }
    #pragma unroll
    for (int o = 32; o > 0; o >>= 1) qq += __shfl_xor(qq, o, 64);
    if (lane == 0) {
        #pragma unroll
        for (int m = 0; m < NWAY; ++m) sm.red[wv*12 + m] = cr[m];
        sm.red[wv*12 + 10] = qq;
    }
    __syncthreads();
    if (threadIdx.x < NWAY) {
        int m = threadIdx.x;
        float CR = sm.red[m] + sm.red[12+m] + sm.red[24+m] + sm.red[36+m];
        float QQ = sm.red[10] + sm.red[22] + sm.red[34] + sm.red[46];
        out[(size_t)qn * NWAY + m] = -(QQ + s2[m] - 2.0f*CR);
    }
}

// Softmax NLL partials: one atomicAdd per block.
__global__ __launch_bounds__(256) void kern_loss(const float* __restrict__ score,
                                                 const int* __restrict__ label,
                                                 float* __restrict__ loss_out) {
    __shared__ float red[4];
    int n = blockIdx.x * 256 + threadIdx.x;
    float lsum = 0.0f;
    if (n < NQRY) {
        const float* srow = score + (size_t)n * NWAY;
        float s[NWAY];
        float mx = -1e30f;
        #pragma unroll
        for (int m = 0; m < NWAY; ++m) { s[m] = srow[m]; mx = fmaxf(mx, s[m]); }
        float se = 0.0f;
        #pragma unroll
        for (int m = 0; m < NWAY; ++m) se += __expf(s[m] - mx);
        float lse = mx + __logf(se);
        lsum = lse - s[label[n]];
    }
    int lane = threadIdx.x & 63, wv = threadIdx.x >> 6;
    #pragma unroll
    for (int o = 32; o > 0; o >>= 1) lsum += __shfl_xor(lsum, o, 64);
    if (lane == 0) red[wv] = lsum;
    __syncthreads();
    if (threadIdx.x == 0)
        atomicAdd(loss_out, (red[0] + red[1] + red[2] + red[3]) * (1.0f / (float)NQRY));
}

extern "C" void kernel_launch(void* const* d_in, const int* in_sizes, int n_in,
                              void* d_out, int out_size, void* d_ws, size_t ws_size,
                              hipStream_t stream) {
    const float* feat = (const float*)d_in[0];
    const float* temp = (const float*)d_in[1];
    const int*   label = (const int*)d_in[2];
    float* out = (float*)d_out;

    float*    support = (float*)d_ws;                        // 20800 f
    float*    s2      = support + NWAY*NTRI;                 // 10 f
    unsigned* table   = (unsigned*)(s2 + 16);                // 2080 u32
    float* loss_slot  = out + (size_t)NQRY * NWAY;

    kern_init<<<(NWAY*NTRI + 255)/256, 256, 0, stream>>>(support, table, loss_slot);
    kern_support<<<NSUP, 256, 0, stream>>>(feat, temp, table, support);
    kern_s2<<<NWAY, 256, 0, stream>>>(support, s2);
    kern_query<<<NQRY, 256, 0, stream>>>(feat, temp, table, support, s2, out);
    kern_loss<<<(NQRY + 255)/256, 256, 0, stream>>>(out, label, loss_slot);
}